// Round 3
// baseline (368.029 us; speedup 1.0000x reference)
//
#include <hip/hip_runtime.h>
#include <math.h>
#include <stdint.h>

// SupConLossTopK, K=8192, D=256, 64 labels, T=0.1, MAX_POS=6, NEG_K=30.
// Round 3:
//  - k_norm   : normalized rows Fn (wave/row)
//  - k_bucket : counting-sort by label; zero g_loss/g_done
//  - k_gram   : per-bucket Gram (sim*10, diag=-3e38). Block = (bucket,
//               16-row group), rows staged whole in LDS (16KB), one column
//               per thread streaming Fn[j]; LDS reads are same-address
//               broadcasts (free). Triangular + mirror store.
//  - k_anchor : wave/anchor. Sim row in 5 regs; top-6 via shfl_xor butterfly;
//               30 random negatives via complement indexing; TRANSPOSED
//               per-lane serial dots (one 6-deep reduce total); fused final
//               mean via device-scope done counter.
// exp(sim - rowmax) ratios == exp(sim) ratios -> no rowmax pass needed.
// Negatives: uniform random 30-subset of different-label indices via counter
// RNG (statistically indistinguishable from reference's rand top-k).

#define NEGK 30
#define MAXP 6
#define MAXBC 320   // max bucket rows (actual ~128 +-11; P(>320) ~ 1e-60)
#define RG 16       // gram rows per block

__device__ __forceinline__ uint64_t mix64(uint64_t z) {
  z += 0x9E3779B97F4A7C15ULL;
  z = (z ^ (z >> 30)) * 0xBF58476D1CE4E5B9ULL;
  z = (z ^ (z >> 27)) * 0x94D049BB133111EBULL;
  return z ^ (z >> 31);
}

__device__ __forceinline__ float wave_reduce_add(float p) {
#pragma unroll
  for (int o = 32; o; o >>= 1) p += __shfl_down(p, o, 64);
  return p;  // lane 0
}

// ---- normalize rows: Fn = F / max(||F||,1e-12), one wave per row ----
__global__ __launch_bounds__(256) void k_norm(const float* __restrict__ F,
                                              float* __restrict__ Fn, int K) {
  const int row = blockIdx.x * 4 + (threadIdx.x >> 6);
  const int lane = threadIdx.x & 63;
  if (row >= K) return;
  const float4 a = ((const float4*)(F + (size_t)row * 256))[lane];
  float p = a.x * a.x + a.y * a.y + a.z * a.z + a.w * a.w;
  p = wave_reduce_add(p);
  p = __shfl(p, 0, 64);
  const float inv = 1.0f / fmaxf(sqrtf(p), 1e-12f);
  float4 o;
  o.x = a.x * inv; o.y = a.y * inv; o.z = a.z * inv; o.w = a.w * inv;
  ((float4*)(Fn + (size_t)row * 256))[lane] = o;
}

// ---- counting sort by label (64 buckets) + offsets + zero accumulators ----
__global__ __launch_bounds__(1024) void k_bucket(const int* __restrict__ labels, int K,
                                                 int* __restrict__ g_start,
                                                 int* __restrict__ g_soff,
                                                 int* __restrict__ g_bucket,
                                                 int* __restrict__ g_loc,
                                                 float* __restrict__ g_loss,
                                                 unsigned int* __restrict__ g_done) {
  __shared__ int cnt[64], start[65], cur[64];
  const int tid = threadIdx.x;
  if (tid < 64) cnt[tid] = 0;
  __syncthreads();
  for (int t = tid; t < K; t += blockDim.x) atomicAdd(&cnt[labels[t] & 63], 1);
  __syncthreads();
  if (tid == 0) {
    int acc = 0, sacc = 0;
    for (int l = 0; l < 64; ++l) {
      start[l] = acc;
      const int B = cnt[l];
      acc += B;
      g_soff[l] = sacc;
      const int Bc = B < MAXBC ? B : MAXBC;
      sacc += Bc * Bc;
    }
    start[64] = acc;
    *g_loss = 0.0f;
    *g_done = 0u;
  }
  __syncthreads();
  if (tid < 64) cur[tid] = start[tid];
  if (tid < 65) g_start[tid] = start[tid];
  __syncthreads();
  for (int t = tid; t < K; t += blockDim.x) {
    const int l = labels[t] & 63;
    const int p = atomicAdd(&cur[l], 1);
    g_bucket[p] = t;
    g_loc[t] = p - start[l];
  }
}

// ---- per-bucket Gram: block = (bucket, 16-row group), col per thread ----
__global__ __launch_bounds__(256) void k_gram(const float* __restrict__ Fn,
                                              const int* __restrict__ g_start,
                                              const int* __restrict__ g_soff,
                                              const int* __restrict__ g_bucket,
                                              float* __restrict__ g_sims) {
  __shared__ float sA[RG * 256];  // 16 KB

  const int b  = blockIdx.x;
  const int rg = blockIdx.y;
  const int bs = g_start[b];
  const int B  = g_start[b + 1] - bs;
  const int Bc = B < MAXBC ? B : MAXBC;
  const int r0 = rg * RG;
  if (r0 >= Bc) return;
  const int nrows = (Bc - r0) < RG ? (Bc - r0) : RG;

  const int tid = threadIdx.x;
  // stage nrows anchor rows whole (coalesced float4)
  for (int t = tid; t < nrows * 64; t += 256) {
    const int r = t >> 6, c4 = t & 63;
    const int gr = g_bucket[bs + r0 + r];
    ((float4*)sA)[r * 64 + c4] = ((const float4*)(Fn + (size_t)gr * 256))[c4];
  }
  __syncthreads();

  float* outb = g_sims + g_soff[b];
  const int ncols = Bc - r0;  // triangular: cols q in [r0, Bc)
  for (int cc = tid; cc < ncols; cc += 256) {
    const int q  = r0 + cc;
    const int gq = g_bucket[bs + q];
    const float* fq = Fn + (size_t)gq * 256;
    float4 acc[RG];
#pragma unroll
    for (int r = 0; r < RG; ++r) acc[r] = make_float4(0, 0, 0, 0);
    for (int k4 = 0; k4 < 64; ++k4) {
      const float4 a = ((const float4*)fq)[k4];
#pragma unroll
      for (int r = 0; r < RG; ++r) {
        const float4 w = ((const float4*)sA)[r * 64 + k4];  // broadcast (free)
        acc[r].x += a.x * w.x; acc[r].y += a.y * w.y;
        acc[r].z += a.z * w.z; acc[r].w += a.w * w.w;
      }
    }
#pragma unroll
    for (int r = 0; r < RG; ++r) {
      if (r < nrows) {
        const int rr = r0 + r;
        const float s = (acc[r].x + acc[r].y + acc[r].z + acc[r].w) * 10.0f;
        const float sv = (rr == q) ? -3.0e38f : s;
        outb[(size_t)rr * Bc + q] = sv;
        if (rr != q) outb[(size_t)q * Bc + rr] = sv;
      }
    }
  }
}

// ---- per-anchor: one wave; reg argmax + transposed negative dots ----
__global__ __launch_bounds__(256) void k_anchor(
    const float* __restrict__ Fn, const int* __restrict__ labels,
    const int* __restrict__ g_start, const int* __restrict__ g_soff,
    const int* __restrict__ g_bucket, const int* __restrict__ g_loc,
    const float* __restrict__ g_sims, float* __restrict__ g_loss,
    unsigned int* __restrict__ g_done, float* __restrict__ out, int K) {
  __shared__ float s_fi[4][256];
  const int wv = threadIdx.x >> 6;
  const int lane = threadIdx.x & 63;
  const int i = blockIdx.x * 4 + wv;  // K multiple of 4

  const int li = labels[i] & 63;
  const int bs = g_start[li];
  const int B  = g_start[li + 1] - bs;
  const int Bc = B < MAXBC ? B : MAXBC;
  const int n_pos = B - 1;
  const int n_neg = K - B;
  int loc = g_loc[i];
  if (loc >= Bc) loc = 0;  // unreachable in practice
  const float* simrow = g_sims + g_soff[li] + (size_t)loc * Bc;

  // stage anchor row (wave-private LDS slice, no block sync needed)
  const float4 av = ((const float4*)(Fn + (size_t)i * 256))[lane];
  ((float4*)s_fi[wv])[lane] = av;

  // sim row -> 5 registers (Bc <= 320)
  float v[5];
#pragma unroll
  for (int rr = 0; rr < 5; ++rr) {
    const int t = lane + rr * 64;
    v[rr] = (t < Bc) ? simrow[t] : -3.4e38f;
  }

  int t6 = n_neg < MAXP ? n_neg : MAXP;
  if (t6 < 1) t6 = 1;
  int take = n_pos < t6 ? n_pos : t6;
  if (n_pos <= 0 || n_neg <= 0) take = 0;

  // top-take positives: register argmax + shfl_xor butterfly
  float num = 0.0f;
  for (int r = 0; r < take; ++r) {
    float best = -3.4e38f;
    int bi = 0x7FFFFFFF;
#pragma unroll
    for (int rr = 0; rr < 5; ++rr) {
      if (v[rr] > best) { best = v[rr]; bi = rr * 64 + lane; }
    }
#pragma unroll
    for (int o = 1; o < 64; o <<= 1) {
      const float ov = __shfl_xor(best, o, 64);
      const int oi = __shfl_xor(bi, o, 64);
      if (ov > best || (ov == best && oi < bi)) { best = ov; bi = oi; }
    }
    num += expf(best);
    const int rsel = bi >> 6;
    if ((bi & 63) == lane) {
#pragma unroll
      for (int rr = 0; rr < 5; ++rr)
        if (rr == rsel) v[rr] = -3.4e38f;
    }
  }

  // sample negatives: lane t draws uniform r in [0,n_neg), dedup via shuffles
  const int target = (take > 0) ? (n_neg < NEGK ? n_neg : NEGK) : 0;
  unsigned int rdraw = 0x40000000u + lane;  // distinct out-of-range sentinel
  if (lane < target) {
    const uint64_t z = mix64(((uint64_t)(uint32_t)i << 32) | (uint32_t)lane);
    rdraw = (unsigned int)(((uint64_t)(uint32_t)z * (uint64_t)n_neg) >> 32);
  }
  for (int round = 0; round < 8; ++round) {
    bool dup = false;
    for (int l2 = 0; l2 < NEGK; ++l2) {
      const unsigned int vv = __shfl(rdraw, l2, 64);
      if (l2 < lane && vv == rdraw) dup = true;
    }
    if (!__any(dup)) break;
    if (dup && lane < target) {
      const uint64_t z =
          mix64(((uint64_t)(uint32_t)i << 32) | (uint32_t)(lane + 64 * (round + 1)));
      rdraw = (unsigned int)(((uint64_t)(uint32_t)z * (uint64_t)n_neg) >> 32);
    }
  }
  int myj = 0;
  if (lane < target) {
    const int pos = (rdraw < (unsigned int)bs) ? (int)rdraw : (int)rdraw + B;
    myj = g_bucket[pos];
  }

  // transposed negative dots: lane t owns negative t (serial over D)
  const float* fj = Fn + (size_t)myj * 256;
  const float* fi = s_fi[wv];
  float4 accv = make_float4(0, 0, 0, 0);
  for (int k4 = 0; k4 < 64; ++k4) {
    const float4 a = ((const float4*)fj)[k4];
    const float4 w = ((const float4*)fi)[k4];  // broadcast (free)
    accv.x += a.x * w.x; accv.y += a.y * w.y;
    accv.z += a.z * w.z; accv.w += a.w * w.w;
  }
  const float dot = accv.x + accv.y + accv.z + accv.w;
  const float e = (lane < target) ? expf(dot * 10.0f) : 0.0f;
  const float wsum = wave_reduce_add(e);

  if (lane == 0) {
    const float denom = num + wsum;
    float ratio = denom > 0.0f ? num / denom : 0.0f;
    ratio = fmaxf(ratio, 1e-8f);
    atomicAdd(g_loss, -logf(ratio));
    __threadfence();
    const unsigned int old = atomicAdd(g_done, 1u);
    if (old == (unsigned int)(K - 1)) {
      __threadfence();
      const float total = atomicAdd(g_loss, 0.0f);  // atomic read of final sum
      out[0] = total / (float)K;
    }
  }
}

extern "C" void kernel_launch(void* const* d_in, const int* in_sizes, int n_in,
                              void* d_out, int out_size, void* d_ws, size_t ws_size,
                              hipStream_t stream) {
  (void)n_in; (void)out_size; (void)ws_size;
  const float* F = (const float*)d_in[0];
  const int* labels = (const int*)d_in[1];
  const int K = in_sizes[1];  // 8192; D=256 hard-assumed
  float* out = (float*)d_out;

  char* ws = (char*)d_ws;
  size_t off = 0;
  float* g_loss   = (float*)(ws + off); off += 256;
  unsigned int* g_done = (unsigned int*)(ws + off); off += 256;
  int*   g_start  = (int*)(ws + off);   off += 512;
  int*   g_soff   = (int*)(ws + off);   off += 256;
  int*   g_bucket = (int*)(ws + off);   off += (size_t)K * 4;
  int*   g_loc    = (int*)(ws + off);   off += (size_t)K * 4;
  off = (off + 255) & ~(size_t)255;
  float* Fn       = (float*)(ws + off); off += (size_t)K * 256 * 4;
  float* g_sims   = (float*)(ws + off); off += (size_t)MAXBC * K * 4;

  k_norm  <<<(K + 3) / 4, 256, 0, stream>>>(F, Fn, K);
  k_bucket<<<1, 1024, 0, stream>>>(labels, K, g_start, g_soff, g_bucket, g_loc,
                                   g_loss, g_done);
  {
    dim3 grid(64, (MAXBC + RG - 1) / RG, 1);
    k_gram<<<grid, 256, 0, stream>>>(Fn, g_start, g_soff, g_bucket, g_sims);
  }
  k_anchor<<<(K + 3) / 4, 256, 0, stream>>>(Fn, labels, g_start, g_soff, g_bucket,
                                            g_loc, g_sims, g_loss, g_done, out, K);
}

// Round 4
// 307.331 us; speedup vs baseline: 1.1975x; 1.1975x over previous
//
#include <hip/hip_runtime.h>
#include <hip/hip_fp16.h>
#include <math.h>
#include <stdint.h>

// SupConLossTopK, K=8192, D=256, 64 labels, T=0.1, MAX_POS=6, NEG_K=30.
// Round 4:
//  - fp16 feature store Fh (4MB, fits per-XCD L2; halves gather lines)
//  - k_gram v4: 32-row groups in LDS (broadcast reads, conflict-free),
//    column-per-thread, v_dot2_f32_f16, triangular + mirror store
//  - k_anchor v3: 4 lanes per negative -> 16 rows in flight per vmem instr,
//    every 64B line fully consumed; one 2-deep reduce per round (vs 30x6
//    shuffle chains); anchor row held in registers; fused final mean.
// exp(sim - rowmax) ratios == exp(sim) ratios -> no rowmax pass.
// Negatives: uniform random 30-subset of different-label indices via counter
// RNG (statistically indistinguishable from reference's rand top-k).

#define NEGK 30
#define MAXP 6
#define MAXBC 320   // max bucket rows (actual ~128 +-11; P(>320) ~ 1e-60)
#define RG2 32      // gram rows per block

typedef _Float16 h2v __attribute__((ext_vector_type(2)));

__device__ __forceinline__ uint64_t mix64(uint64_t z) {
  z += 0x9E3779B97F4A7C15ULL;
  z = (z ^ (z >> 30)) * 0xBF58476D1CE4E5B9ULL;
  z = (z ^ (z >> 27)) * 0x94D049BB133111EBULL;
  return z ^ (z >> 31);
}

__device__ __forceinline__ float wave_reduce_add(float p) {
#pragma unroll
  for (int o = 32; o; o >>= 1) p += __shfl_down(p, o, 64);
  return p;  // lane 0
}

// dot of 8 packed halfs (one 16B chunk) accumulated into acc
__device__ __forceinline__ float dot8h(uint4 a, uint4 b, float acc) {
  const h2v* pa = (const h2v*)&a;
  const h2v* pb = (const h2v*)&b;
#if __has_builtin(__builtin_amdgcn_fdot2)
#pragma unroll
  for (int q = 0; q < 4; ++q) acc = __builtin_amdgcn_fdot2(pa[q], pb[q], acc, false);
#else
#pragma unroll
  for (int q = 0; q < 4; ++q)
    acc += (float)pa[q].x * (float)pb[q].x + (float)pa[q].y * (float)pb[q].y;
#endif
  return acc;
}

// ---- normalize rows -> fp16 store, one wave per row ----
__global__ __launch_bounds__(256) void k_norm(const float* __restrict__ F,
                                              __half* __restrict__ Fh, int K) {
  const int row = blockIdx.x * 4 + (threadIdx.x >> 6);
  const int lane = threadIdx.x & 63;
  if (row >= K) return;
  const float4 a = ((const float4*)(F + (size_t)row * 256))[lane];
  float p = a.x * a.x + a.y * a.y + a.z * a.z + a.w * a.w;
  p = wave_reduce_add(p);
  p = __shfl(p, 0, 64);
  const float inv = 1.0f / fmaxf(sqrtf(p), 1e-12f);
  union { __half2 h[2]; uint2 u; } cv;
  cv.h[0] = __float22half2_rn(make_float2(a.x * inv, a.y * inv));
  cv.h[1] = __float22half2_rn(make_float2(a.z * inv, a.w * inv));
  ((uint2*)(Fh + (size_t)row * 256))[lane] = cv.u;
}

// ---- counting sort by label (64 buckets) + offsets + zero accumulators ----
__global__ __launch_bounds__(1024) void k_bucket(const int* __restrict__ labels, int K,
                                                 int* __restrict__ g_start,
                                                 int* __restrict__ g_soff,
                                                 int* __restrict__ g_bucket,
                                                 int* __restrict__ g_loc,
                                                 float* __restrict__ g_loss,
                                                 unsigned int* __restrict__ g_done) {
  __shared__ int cnt[64], start[65], cur[64];
  const int tid = threadIdx.x;
  if (tid < 64) cnt[tid] = 0;
  __syncthreads();
  for (int t = tid; t < K; t += blockDim.x) atomicAdd(&cnt[labels[t] & 63], 1);
  __syncthreads();
  if (tid == 0) {
    int acc = 0, sacc = 0;
    for (int l = 0; l < 64; ++l) {
      start[l] = acc;
      const int B = cnt[l];
      acc += B;
      g_soff[l] = sacc;
      const int Bc = B < MAXBC ? B : MAXBC;
      sacc += Bc * Bc;
    }
    start[64] = acc;
    *g_loss = 0.0f;
    *g_done = 0u;
  }
  __syncthreads();
  if (tid < 64) cur[tid] = start[tid];
  if (tid < 65) g_start[tid] = start[tid];
  __syncthreads();
  for (int t = tid; t < K; t += blockDim.x) {
    const int l = labels[t] & 63;
    const int p = atomicAdd(&cur[l], 1);
    g_bucket[p] = t;
    g_loc[t] = p - start[l];
  }
}

// ---- per-bucket Gram (sim*10, diag=-3e38): 32-row groups, col per thread ----
__global__ __launch_bounds__(128) void k_gram(const __half* __restrict__ Fh,
                                              const int* __restrict__ g_start,
                                              const int* __restrict__ g_soff,
                                              const int* __restrict__ g_bucket,
                                              float* __restrict__ g_sims) {
  __shared__ uint4 sA[RG2 * 32];  // 32 rows x 512B = 16KB

  const int b  = blockIdx.x;
  const int rg = blockIdx.y;
  const int bs = g_start[b];
  const int B  = g_start[b + 1] - bs;
  const int Bc = B < MAXBC ? B : MAXBC;
  const int r0 = rg * RG2;
  if (r0 >= Bc) return;
  const int tid = threadIdx.x;

  // stage rows r0..r0+31 (fp16, coalesced 16B chunks; zero-fill past Bc)
  for (int t = tid; t < RG2 * 32; t += 128) {
    const int r = t >> 5, c = t & 31;
    uint4 v = make_uint4(0, 0, 0, 0);
    if (r0 + r < Bc) {
      const int gr = g_bucket[bs + r0 + r];
      v = ((const uint4*)(Fh + (size_t)gr * 256))[c];
    }
    sA[r * 32 + c] = v;
  }
  __syncthreads();

  float* outb = g_sims + g_soff[b];
  for (int cc = r0 + tid; cc < Bc; cc += 128) {
    const int gq = g_bucket[bs + cc];
    const uint4* fq = (const uint4*)(Fh + (size_t)gq * 256);
    float acc[RG2];
#pragma unroll
    for (int r = 0; r < RG2; ++r) acc[r] = 0.0f;
    for (int k = 0; k < 32; ++k) {
      const uint4 a = fq[k];
#pragma unroll
      for (int r = 0; r < RG2; ++r)
        acc[r] = dot8h(sA[r * 32 + k], a, acc[r]);  // LDS broadcast (free)
    }
#pragma unroll
    for (int r = 0; r < RG2; ++r) {
      const int rr = r0 + r;
      if (rr >= Bc || cc < rr) continue;  // upper triangle only
      const float sv = (rr == cc) ? -3.0e38f : acc[r] * 10.0f;
      outb[(size_t)rr * Bc + cc] = sv;
      if (rr != cc) outb[(size_t)cc * Bc + rr] = sv;
    }
  }
}

// ---- per-anchor: one wave; reg argmax + 4-lane-group negative dots ----
__global__ __launch_bounds__(256) void k_anchor(
    const __half* __restrict__ Fh, const int* __restrict__ labels,
    const int* __restrict__ g_start, const int* __restrict__ g_soff,
    const int* __restrict__ g_bucket, const int* __restrict__ g_loc,
    const float* __restrict__ g_sims, float* __restrict__ g_loss,
    unsigned int* __restrict__ g_done, float* __restrict__ out, int K) {
  const int wv = threadIdx.x >> 6;
  const int lane = threadIdx.x & 63;
  const int i = blockIdx.x * 4 + wv;  // K multiple of 4

  const int li = labels[i] & 63;
  const int bs = g_start[li];
  const int B  = g_start[li + 1] - bs;
  const int Bc = B < MAXBC ? B : MAXBC;
  const int n_pos = B - 1;
  const int n_neg = K - B;
  int loc = g_loc[i];
  if (loc >= Bc) loc = 0;  // unreachable in practice
  const float* simrow = g_sims + g_soff[li] + (size_t)loc * Bc;

  // anchor row chunks for this lane's sub-position (4 lanes cover a row)
  const int s = lane & 3, g = lane >> 2;
  const uint4* fi4 = (const uint4*)(Fh + (size_t)i * 256);
  uint4 fi[8];
#pragma unroll
  for (int k = 0; k < 8; ++k) fi[k] = fi4[k * 4 + s];

  // sim row -> 5 registers (Bc <= 320)
  float v[5];
#pragma unroll
  for (int rr = 0; rr < 5; ++rr) {
    const int t = lane + rr * 64;
    v[rr] = (t < Bc) ? simrow[t] : -3.4e38f;
  }

  int t6 = n_neg < MAXP ? n_neg : MAXP;
  if (t6 < 1) t6 = 1;
  int take = n_pos < t6 ? n_pos : t6;
  if (n_pos <= 0 || n_neg <= 0) take = 0;

  // top-take positives: register argmax + shfl_xor butterfly
  float num = 0.0f;
  for (int r = 0; r < take; ++r) {
    float best = -3.4e38f;
    int bi = 0x7FFFFFFF;
#pragma unroll
    for (int rr = 0; rr < 5; ++rr) {
      if (v[rr] > best) { best = v[rr]; bi = rr * 64 + lane; }
    }
#pragma unroll
    for (int o = 1; o < 64; o <<= 1) {
      const float ov = __shfl_xor(best, o, 64);
      const int oi = __shfl_xor(bi, o, 64);
      if (ov > best || (ov == best && oi < bi)) { best = ov; bi = oi; }
    }
    num += expf(best);
    const int rsel = bi >> 6;
    if ((bi & 63) == lane) {
#pragma unroll
      for (int rr = 0; rr < 5; ++rr)
        if (rr == rsel) v[rr] = -3.4e38f;
    }
  }

  // sample negatives: lane t draws uniform r in [0,n_neg), dedup via shuffles
  const int target = (take > 0) ? (n_neg < NEGK ? n_neg : NEGK) : 0;
  unsigned int rdraw = 0x40000000u + lane;  // distinct out-of-range sentinel
  if (lane < target) {
    const uint64_t z = mix64(((uint64_t)(uint32_t)i << 32) | (uint32_t)lane);
    rdraw = (unsigned int)(((uint64_t)(uint32_t)z * (uint64_t)n_neg) >> 32);
  }
  for (int round = 0; round < 8; ++round) {
    bool dup = false;
    for (int l2 = 0; l2 < NEGK; ++l2) {
      const unsigned int vv = __shfl(rdraw, l2, 64);
      if (l2 < lane && vv == rdraw) dup = true;
    }
    if (!__any(dup)) break;
    if (dup && lane < target) {
      const uint64_t z =
          mix64(((uint64_t)(uint32_t)i << 32) | (uint32_t)(lane + 64 * (round + 1)));
      rdraw = (unsigned int)(((uint64_t)(uint32_t)z * (uint64_t)n_neg) >> 32);
    }
  }
  int myj = 0;
  if (lane < target) {
    const int pos = (rdraw < (unsigned int)bs) ? (int)rdraw : (int)rdraw + B;
    myj = g_bucket[pos];
  }

  // negative dots: 4 lanes per negative, 16 rows in flight per vmem instr;
  // each wave instruction reads 16 fully-consumed 64B lines.
  float e = 0.0f;
#pragma unroll
  for (int r = 0; r < 2; ++r) {
    const int t = r * 16 + g;
    const int j = __shfl(myj, t, 64);
    const uint4* fj = (const uint4*)(Fh + (size_t)j * 256);
    float d = 0.0f;
#pragma unroll
    for (int k = 0; k < 8; ++k) d = dot8h(fj[k * 4 + s], fi[k], d);
    d += __shfl_xor(d, 1, 64);
    d += __shfl_xor(d, 2, 64);
    if (s == 0 && t < target) e += expf(d * 10.0f);
  }
  const float wsum = wave_reduce_add(e);

  if (lane == 0) {
    const float denom = num + wsum;
    float ratio = denom > 0.0f ? num / denom : 0.0f;
    ratio = fmaxf(ratio, 1e-8f);
    atomicAdd(g_loss, -logf(ratio));
    __threadfence();
    const unsigned int old = atomicAdd(g_done, 1u);
    if (old == (unsigned int)(K - 1)) {
      __threadfence();
      const float total = atomicAdd(g_loss, 0.0f);  // atomic read of final sum
      out[0] = total / (float)K;
    }
  }
}

extern "C" void kernel_launch(void* const* d_in, const int* in_sizes, int n_in,
                              void* d_out, int out_size, void* d_ws, size_t ws_size,
                              hipStream_t stream) {
  (void)n_in; (void)out_size; (void)ws_size;
  const float* F = (const float*)d_in[0];
  const int* labels = (const int*)d_in[1];
  const int K = in_sizes[1];  // 8192; D=256 hard-assumed
  float* out = (float*)d_out;

  char* ws = (char*)d_ws;
  size_t off = 0;
  float* g_loss   = (float*)(ws + off); off += 256;
  unsigned int* g_done = (unsigned int*)(ws + off); off += 256;
  int*   g_start  = (int*)(ws + off);   off += 512;
  int*   g_soff   = (int*)(ws + off);   off += 256;
  int*   g_bucket = (int*)(ws + off);   off += (size_t)K * 4;
  int*   g_loc    = (int*)(ws + off);   off += (size_t)K * 4;
  off = (off + 255) & ~(size_t)255;
  __half* Fh      = (__half*)(ws + off); off += (size_t)K * 256 * 2;
  float* g_sims   = (float*)(ws + off);  off += (size_t)MAXBC * K * 4;

  k_norm  <<<(K + 3) / 4, 256, 0, stream>>>(F, Fh, K);
  k_bucket<<<1, 1024, 0, stream>>>(labels, K, g_start, g_soff, g_bucket, g_loc,
                                   g_loss, g_done);
  {
    dim3 grid(64, (MAXBC + RG2 - 1) / RG2, 1);
    k_gram<<<grid, 128, 0, stream>>>(Fh, g_start, g_soff, g_bucket, g_sims);
  }
  k_anchor<<<(K + 3) / 4, 256, 0, stream>>>(Fh, labels, g_start, g_soff, g_bucket,
                                            g_loc, g_sims, g_loss, g_done, out, K);
}

// Round 5
// 144.902 us; speedup vs baseline: 2.5399x; 2.1210x over previous
//
#include <hip/hip_runtime.h>
#include <hip/hip_fp16.h>
#include <math.h>
#include <stdint.h>

// SupConLossTopK, K=8192, D=256, 64 labels, T=0.1, MAX_POS=6, NEG_K=30.
// Round 5:
//  - REMOVED the same-address atomic epilogue (round-4's 204us was 16384
//    atomics + 8192 device fences on two cache lines serializing at L2:
//    ~30cy each ~= the whole kernel duration). Per-wave loss -> g_part[i],
//    tiny k_final reduction kernel.
//  - g_meta[i] = (bucket_start, bucket_size, loc, sims_off) packed int4:
//    one load replaces the labels->g_start->g_soff->g_loc pointer chase.
//  - k_prep fuses normalize (blocks 0..K/4-1) + bucket sort (block K/4).
//  - fp16 feature store (4MB, L2-resident), 4-lanes-per-negative gather
//    dots (16 fully-consumed 64B lines per vmem instr) as in round 4.
// exp(sim - rowmax) ratios == exp(sim) ratios -> no rowmax pass.
// Negatives: uniform random 30-subset of different-label indices via counter
// RNG (statistically indistinguishable from reference's rand top-k).

#define NEGK 30
#define MAXP 6
#define MAXBC 320   // max bucket rows (actual ~128 +-11; P(>320) ~ 1e-60)
#define RG2 32      // gram rows per block

typedef _Float16 h2v __attribute__((ext_vector_type(2)));

__device__ __forceinline__ uint64_t mix64(uint64_t z) {
  z += 0x9E3779B97F4A7C15ULL;
  z = (z ^ (z >> 30)) * 0xBF58476D1CE4E5B9ULL;
  z = (z ^ (z >> 27)) * 0x94D049BB133111EBULL;
  return z ^ (z >> 31);
}

__device__ __forceinline__ float wave_reduce_add(float p) {
#pragma unroll
  for (int o = 32; o; o >>= 1) p += __shfl_down(p, o, 64);
  return p;  // lane 0
}

// dot of 8 packed halfs (one 16B chunk) accumulated into acc
__device__ __forceinline__ float dot8h(uint4 a, uint4 b, float acc) {
  const h2v* pa = (const h2v*)&a;
  const h2v* pb = (const h2v*)&b;
#if __has_builtin(__builtin_amdgcn_fdot2)
#pragma unroll
  for (int q = 0; q < 4; ++q) acc = __builtin_amdgcn_fdot2(pa[q], pb[q], acc, false);
#else
#pragma unroll
  for (int q = 0; q < 4; ++q)
    acc += (float)pa[q].x * (float)pb[q].x + (float)pa[q].y * (float)pb[q].y;
#endif
  return acc;
}

// ---- fused: blocks 0..K/4-1 normalize rows -> fp16; block K/4 bucket sort --
__global__ __launch_bounds__(256) void k_prep(const float* __restrict__ F,
                                              const int* __restrict__ labels, int K,
                                              __half* __restrict__ Fh,
                                              int* __restrict__ g_start,
                                              int* __restrict__ g_soff,
                                              int* __restrict__ g_bucket,
                                              int4* __restrict__ g_meta) {
  __shared__ int cnt[64], start[65], cur[64], soff_s[64];
  const int tid = threadIdx.x;

  if ((int)blockIdx.x < K / 4) {
    const int row = blockIdx.x * 4 + (tid >> 6);
    const int lane = tid & 63;
    const float4 a = ((const float4*)(F + (size_t)row * 256))[lane];
    float p = a.x * a.x + a.y * a.y + a.z * a.z + a.w * a.w;
    p = wave_reduce_add(p);
    p = __shfl(p, 0, 64);
    const float inv = 1.0f / fmaxf(sqrtf(p), 1e-12f);
    union { __half2 h[2]; uint2 u; } cv;
    cv.h[0] = __float22half2_rn(make_float2(a.x * inv, a.y * inv));
    cv.h[1] = __float22half2_rn(make_float2(a.z * inv, a.w * inv));
    ((uint2*)(Fh + (size_t)row * 256))[lane] = cv.u;
    return;
  }

  // bucket block
  if (tid < 64) cnt[tid] = 0;
  __syncthreads();
  for (int t = tid; t < K; t += 256) atomicAdd(&cnt[labels[t] & 63], 1);
  __syncthreads();
  if (tid == 0) {
    int acc = 0, sacc = 0;
    for (int l = 0; l < 64; ++l) {
      start[l] = acc;
      const int B = cnt[l];
      acc += B;
      soff_s[l] = sacc;
      const int Bc = B < MAXBC ? B : MAXBC;
      sacc += Bc * Bc;
    }
    start[64] = acc;
  }
  __syncthreads();
  if (tid < 64) { cur[tid] = start[tid]; g_soff[tid] = soff_s[tid]; }
  if (tid < 65) g_start[tid] = start[tid];
  __syncthreads();
  for (int t = tid; t < K; t += 256) {
    const int l = labels[t] & 63;
    const int p = atomicAdd(&cur[l], 1);
    g_bucket[p] = t;
    g_meta[t] = make_int4(start[l], cnt[l], p - start[l], soff_s[l]);
  }
}

// ---- per-bucket Gram (sim*10, diag=-3e38): 32-row groups, col per thread ----
__global__ __launch_bounds__(128) void k_gram(const __half* __restrict__ Fh,
                                              const int* __restrict__ g_start,
                                              const int* __restrict__ g_soff,
                                              const int* __restrict__ g_bucket,
                                              float* __restrict__ g_sims) {
  __shared__ uint4 sA[RG2 * 32];  // 32 rows x 512B = 16KB

  const int b  = blockIdx.x;
  const int rg = blockIdx.y;
  const int bs = g_start[b];
  const int B  = g_start[b + 1] - bs;
  const int Bc = B < MAXBC ? B : MAXBC;
  const int r0 = rg * RG2;
  if (r0 >= Bc) return;
  const int tid = threadIdx.x;

  // stage rows r0..r0+31 (fp16, coalesced 16B chunks; zero-fill past Bc)
  for (int t = tid; t < RG2 * 32; t += 128) {
    const int r = t >> 5, c = t & 31;
    uint4 v = make_uint4(0, 0, 0, 0);
    if (r0 + r < Bc) {
      const int gr = g_bucket[bs + r0 + r];
      v = ((const uint4*)(Fh + (size_t)gr * 256))[c];
    }
    sA[r * 32 + c] = v;
  }
  __syncthreads();

  float* outb = g_sims + g_soff[b];
  for (int cc = r0 + tid; cc < Bc; cc += 128) {
    const int gq = g_bucket[bs + cc];
    const uint4* fq = (const uint4*)(Fh + (size_t)gq * 256);
    float acc[RG2];
#pragma unroll
    for (int r = 0; r < RG2; ++r) acc[r] = 0.0f;
    for (int k = 0; k < 32; ++k) {
      const uint4 a = fq[k];
#pragma unroll
      for (int r = 0; r < RG2; ++r)
        acc[r] = dot8h(sA[r * 32 + k], a, acc[r]);  // LDS broadcast (free)
    }
#pragma unroll
    for (int r = 0; r < RG2; ++r) {
      const int rr = r0 + r;
      if (rr >= Bc || cc < rr) continue;  // upper triangle only
      const float sv = (rr == cc) ? -3.0e38f : acc[r] * 10.0f;
      outb[(size_t)rr * Bc + cc] = sv;
      if (rr != cc) outb[(size_t)cc * Bc + rr] = sv;
    }
  }
}

// ---- per-anchor: one wave; reg argmax + 4-lane-group negative dots ----
__global__ __launch_bounds__(256) void k_anchor(
    const __half* __restrict__ Fh, const int* __restrict__ g_bucket,
    const int4* __restrict__ g_meta, const float* __restrict__ g_sims,
    float* __restrict__ g_part, int K) {
  const int wv = threadIdx.x >> 6;
  const int lane = threadIdx.x & 63;
  const int i = blockIdx.x * 4 + wv;  // K multiple of 4

  const int4 mt = g_meta[i];          // (bucket_start, bucket_size, loc, soff)
  const int bs = mt.x, B = mt.y;
  const int Bc = B < MAXBC ? B : MAXBC;
  int loc = mt.z;
  if (loc >= Bc) loc = 0;             // unreachable in practice
  const int n_pos = B - 1;
  const int n_neg = K - B;
  const float* simrow = g_sims + mt.w + (size_t)loc * Bc;

  // anchor row chunks for this lane's sub-position (4 lanes cover a row)
  const int s = lane & 3, g = lane >> 2;
  const uint4* fi4 = (const uint4*)(Fh + (size_t)i * 256);
  uint4 fi[8];
#pragma unroll
  for (int k = 0; k < 8; ++k) fi[k] = fi4[k * 4 + s];

  // sim row -> 5 registers (Bc <= 320)
  float v[5];
#pragma unroll
  for (int rr = 0; rr < 5; ++rr) {
    const int t = lane + rr * 64;
    v[rr] = (t < Bc) ? simrow[t] : -3.4e38f;
  }

  int t6 = n_neg < MAXP ? n_neg : MAXP;
  if (t6 < 1) t6 = 1;
  int take = n_pos < t6 ? n_pos : t6;
  if (n_pos <= 0 || n_neg <= 0) take = 0;

  // top-take positives: register argmax + shfl_xor butterfly
  float num = 0.0f;
  for (int r = 0; r < take; ++r) {
    float best = -3.4e38f;
    int bi = 0x7FFFFFFF;
#pragma unroll
    for (int rr = 0; rr < 5; ++rr) {
      if (v[rr] > best) { best = v[rr]; bi = rr * 64 + lane; }
    }
#pragma unroll
    for (int o = 1; o < 64; o <<= 1) {
      const float ov = __shfl_xor(best, o, 64);
      const int oi = __shfl_xor(bi, o, 64);
      if (ov > best || (ov == best && oi < bi)) { best = ov; bi = oi; }
    }
    num += expf(best);
    const int rsel = bi >> 6;
    if ((bi & 63) == lane) {
#pragma unroll
      for (int rr = 0; rr < 5; ++rr)
        if (rr == rsel) v[rr] = -3.4e38f;
    }
  }

  // sample negatives: lane t draws uniform r in [0,n_neg), dedup via shuffles
  const int target = (take > 0) ? (n_neg < NEGK ? n_neg : NEGK) : 0;
  unsigned int rdraw = 0x40000000u + lane;  // distinct out-of-range sentinel
  if (lane < target) {
    const uint64_t z = mix64(((uint64_t)(uint32_t)i << 32) | (uint32_t)lane);
    rdraw = (unsigned int)(((uint64_t)(uint32_t)z * (uint64_t)n_neg) >> 32);
  }
  for (int round = 0; round < 8; ++round) {
    bool dup = false;
    for (int l2 = 0; l2 < NEGK; ++l2) {
      const unsigned int vv = __shfl(rdraw, l2, 64);
      if (l2 < lane && vv == rdraw) dup = true;
    }
    if (!__any(dup)) break;
    if (dup && lane < target) {
      const uint64_t z =
          mix64(((uint64_t)(uint32_t)i << 32) | (uint32_t)(lane + 64 * (round + 1)));
      rdraw = (unsigned int)(((uint64_t)(uint32_t)z * (uint64_t)n_neg) >> 32);
    }
  }
  int myj = 0;
  if (lane < target) {
    const int pos = (rdraw < (unsigned int)bs) ? (int)rdraw : (int)rdraw + B;
    myj = g_bucket[pos];
  }

  // negative dots: 4 lanes per negative, 16 rows in flight per vmem instr;
  // each wave instruction reads 16 fully-consumed 64B lines.
  float e = 0.0f;
#pragma unroll
  for (int r = 0; r < 2; ++r) {
    const int t = r * 16 + g;
    const int j = __shfl(myj, t, 64);
    const uint4* fj = (const uint4*)(Fh + (size_t)j * 256);
    float d = 0.0f;
#pragma unroll
    for (int k = 0; k < 8; ++k) d = dot8h(fj[k * 4 + s], fi[k], d);
    d += __shfl_xor(d, 1, 64);
    d += __shfl_xor(d, 2, 64);
    if (s == 0 && t < target) e += expf(d * 10.0f);
  }
  const float wsum = wave_reduce_add(e);

  if (lane == 0) {
    const float denom = num + wsum;
    float ratio = denom > 0.0f ? num / denom : 0.0f;
    ratio = fmaxf(ratio, 1e-8f);
    g_part[i] = -logf(ratio);           // plain store, no atomics
  }
}

// ---- reduce 8192 per-anchor losses -> mean ----
__global__ __launch_bounds__(1024) void k_final(const float* __restrict__ g_part,
                                                float* __restrict__ out, int K) {
  __shared__ float s[16];
  float p = 0.0f;
  for (int t = threadIdx.x; t < K; t += 1024) p += g_part[t];
  p = wave_reduce_add(p);
  if ((threadIdx.x & 63) == 0) s[threadIdx.x >> 6] = p;
  __syncthreads();
  if (threadIdx.x == 0) {
    float tot = 0.0f;
#pragma unroll
    for (int w = 0; w < 16; ++w) tot += s[w];
    out[0] = tot / (float)K;
  }
}

extern "C" void kernel_launch(void* const* d_in, const int* in_sizes, int n_in,
                              void* d_out, int out_size, void* d_ws, size_t ws_size,
                              hipStream_t stream) {
  (void)n_in; (void)out_size; (void)ws_size;
  const float* F = (const float*)d_in[0];
  const int* labels = (const int*)d_in[1];
  const int K = in_sizes[1];  // 8192; D=256 hard-assumed
  float* out = (float*)d_out;

  char* ws = (char*)d_ws;
  size_t off = 0;
  int*   g_start  = (int*)(ws + off);   off += 512;
  int*   g_soff   = (int*)(ws + off);   off += 256;
  int*   g_bucket = (int*)(ws + off);   off += (size_t)K * 4;
  float* g_part   = (float*)(ws + off); off += (size_t)K * 4;
  off = (off + 255) & ~(size_t)255;
  int4*  g_meta   = (int4*)(ws + off);  off += (size_t)K * 16;
  __half* Fh      = (__half*)(ws + off); off += (size_t)K * 256 * 2;
  float* g_sims   = (float*)(ws + off);  off += (size_t)MAXBC * K * 4;

  k_prep<<<K / 4 + 1, 256, 0, stream>>>(F, labels, K, Fh, g_start, g_soff,
                                        g_bucket, g_meta);
  {
    dim3 grid(64, (MAXBC + RG2 - 1) / RG2, 1);
    k_gram<<<grid, 128, 0, stream>>>(Fh, g_start, g_soff, g_bucket, g_sims);
  }
  k_anchor<<<K / 4, 256, 0, stream>>>(Fh, g_bucket, g_meta, g_sims, g_part, K);
  k_final<<<1, 1024, 0, stream>>>(g_part, out, K);
}

// Round 6
// 121.839 us; speedup vs baseline: 3.0206x; 1.1893x over previous
//
#include <hip/hip_runtime.h>
#include <hip/hip_fp16.h>
#include <math.h>
#include <stdint.h>

// SupConLossTopK, K=8192, D=256, 64 labels, T=0.1, MAX_POS=6, NEG_K=30.
// Round 6:
//  - k_gram v5: round-5's k_gram was a parallelism shortage (2.6% occupancy,
//    ~512 working waves grinding serial 4096-fdot2 loops -> 45us for ~2us of
//    math). New tiling: block = 32 rows x 64 cols of one bucket (grid
//    64x10x5 -> ~512 working blocks ~= 2048 waves), 32 rows staged in 16KB
//    LDS shared by 4 waves (compute reads are wave-uniform broadcasts,
//    conflict-free), wave owns 8 rows, lane owns one column with 4-deep
//    gather prefetch. Full-square (no mirror stores; all stores coalesced).
//  - rest unchanged from round 5 (no same-address atomics anywhere).
// exp(sim - rowmax) ratios == exp(sim) ratios -> no rowmax pass.
// Negatives: uniform random 30-subset of different-label indices via counter
// RNG (statistically indistinguishable from reference's rand top-k).

#define NEGK 30
#define MAXP 6
#define MAXBC 320   // max bucket rows (actual ~128 +-11; P(>320) ~ 1e-60)
#define RGB 32      // gram rows per block
#define CGB 64      // gram cols per block

typedef _Float16 h2v __attribute__((ext_vector_type(2)));

__device__ __forceinline__ uint64_t mix64(uint64_t z) {
  z += 0x9E3779B97F4A7C15ULL;
  z = (z ^ (z >> 30)) * 0xBF58476D1CE4E5B9ULL;
  z = (z ^ (z >> 27)) * 0x94D049BB133111EBULL;
  return z ^ (z >> 31);
}

__device__ __forceinline__ float wave_reduce_add(float p) {
#pragma unroll
  for (int o = 32; o; o >>= 1) p += __shfl_down(p, o, 64);
  return p;  // lane 0
}

// dot of 8 packed halfs (one 16B chunk) accumulated into acc
__device__ __forceinline__ float dot8h(uint4 a, uint4 b, float acc) {
  const h2v* pa = (const h2v*)&a;
  const h2v* pb = (const h2v*)&b;
#if __has_builtin(__builtin_amdgcn_fdot2)
#pragma unroll
  for (int q = 0; q < 4; ++q) acc = __builtin_amdgcn_fdot2(pa[q], pb[q], acc, false);
#else
#pragma unroll
  for (int q = 0; q < 4; ++q)
    acc += (float)pa[q].x * (float)pb[q].x + (float)pa[q].y * (float)pb[q].y;
#endif
  return acc;
}

// ---- fused: blocks 0..K/4-1 normalize rows -> fp16; block K/4 bucket sort --
__global__ __launch_bounds__(256) void k_prep(const float* __restrict__ F,
                                              const int* __restrict__ labels, int K,
                                              __half* __restrict__ Fh,
                                              int* __restrict__ g_start,
                                              int* __restrict__ g_soff,
                                              int* __restrict__ g_bucket,
                                              int4* __restrict__ g_meta) {
  __shared__ int cnt[64], start[65], cur[64], soff_s[64];
  const int tid = threadIdx.x;

  if ((int)blockIdx.x < K / 4) {
    const int row = blockIdx.x * 4 + (tid >> 6);
    const int lane = tid & 63;
    const float4 a = ((const float4*)(F + (size_t)row * 256))[lane];
    float p = a.x * a.x + a.y * a.y + a.z * a.z + a.w * a.w;
    p = wave_reduce_add(p);
    p = __shfl(p, 0, 64);
    const float inv = 1.0f / fmaxf(sqrtf(p), 1e-12f);
    union { __half2 h[2]; uint2 u; } cv;
    cv.h[0] = __float22half2_rn(make_float2(a.x * inv, a.y * inv));
    cv.h[1] = __float22half2_rn(make_float2(a.z * inv, a.w * inv));
    ((uint2*)(Fh + (size_t)row * 256))[lane] = cv.u;
    return;
  }

  // bucket block
  if (tid < 64) cnt[tid] = 0;
  __syncthreads();
  for (int t = tid; t < K; t += 256) atomicAdd(&cnt[labels[t] & 63], 1);
  __syncthreads();
  if (tid == 0) {
    int acc = 0, sacc = 0;
    for (int l = 0; l < 64; ++l) {
      start[l] = acc;
      const int B = cnt[l];
      acc += B;
      soff_s[l] = sacc;
      const int Bc = B < MAXBC ? B : MAXBC;
      sacc += Bc * Bc;
    }
    start[64] = acc;
  }
  __syncthreads();
  if (tid < 64) { cur[tid] = start[tid]; g_soff[tid] = soff_s[tid]; }
  if (tid < 65) g_start[tid] = start[tid];
  __syncthreads();
  for (int t = tid; t < K; t += 256) {
    const int l = labels[t] & 63;
    const int p = atomicAdd(&cur[l], 1);
    g_bucket[p] = t;
    g_meta[t] = make_int4(start[l], cnt[l], p - start[l], soff_s[l]);
  }
}

// ---- per-bucket Gram (sim*10, diag=-3e38): 32x64 tiles, 4 waves/block ----
__global__ __launch_bounds__(256) void k_gram(const __half* __restrict__ Fh,
                                              const int* __restrict__ g_start,
                                              const int* __restrict__ g_soff,
                                              const int* __restrict__ g_bucket,
                                              float* __restrict__ g_sims) {
  __shared__ uint4 sA[RGB * 32];  // 32 rows x 512B = 16KB

  const int b  = blockIdx.x;
  const int bs = g_start[b];
  const int B  = g_start[b + 1] - bs;
  const int Bc = B < MAXBC ? B : MAXBC;
  const int r0 = blockIdx.y * RGB;
  const int c0 = blockIdx.z * CGB;
  if (r0 >= Bc || c0 >= Bc) return;
  const int tid = threadIdx.x;

  // stage 32 rows (fp16, 16B chunks; clamped gather for OOB rows)
  for (int u = tid; u < RGB * 32; u += 256) {
    const int r = u >> 5, c = u & 31;
    const int rr = r0 + r;
    const int gr = g_bucket[bs + (rr < Bc ? rr : Bc - 1)];
    sA[u] = ((const uint4*)(Fh + (size_t)gr * 256))[c];
  }
  __syncthreads();

  const int wv = tid >> 6, lane = tid & 63;
  const int cc = c0 + lane;
  const int gq = g_bucket[bs + (cc < Bc ? cc : Bc - 1)];
  const uint4* fq = (const uint4*)(Fh + (size_t)gq * 256);
  const uint4* sw = sA + wv * 8 * 32;  // this wave's 8 rows

  float acc[8];
#pragma unroll
  for (int r = 0; r < 8; ++r) acc[r] = 0.0f;

  for (int k = 0; k < 32; k += 4) {
    // 4 independent gathers in flight per iteration
    const uint4 a0 = fq[k], a1 = fq[k + 1], a2 = fq[k + 2], a3 = fq[k + 3];
#pragma unroll
    for (int r = 0; r < 8; ++r) {
      float t = acc[r];
      t = dot8h(sw[r * 32 + k    ], a0, t);   // LDS wave-uniform broadcast
      t = dot8h(sw[r * 32 + k + 1], a1, t);
      t = dot8h(sw[r * 32 + k + 2], a2, t);
      t = dot8h(sw[r * 32 + k + 3], a3, t);
      acc[r] = t;
    }
  }

  if (cc < Bc) {
    float* outb = g_sims + g_soff[b];
#pragma unroll
    for (int r = 0; r < 8; ++r) {
      const int rr = r0 + wv * 8 + r;
      if (rr < Bc)
        outb[(size_t)rr * Bc + cc] = (rr == cc) ? -3.0e38f : acc[r] * 10.0f;
    }
  }
}

// ---- per-anchor: one wave; reg argmax + 4-lane-group negative dots ----
__global__ __launch_bounds__(256) void k_anchor(
    const __half* __restrict__ Fh, const int* __restrict__ g_bucket,
    const int4* __restrict__ g_meta, const float* __restrict__ g_sims,
    float* __restrict__ g_part, int K) {
  const int wv = threadIdx.x >> 6;
  const int lane = threadIdx.x & 63;
  const int i = blockIdx.x * 4 + wv;  // K multiple of 4

  const int4 mt = g_meta[i];          // (bucket_start, bucket_size, loc, soff)
  const int bs = mt.x, B = mt.y;
  const int Bc = B < MAXBC ? B : MAXBC;
  int loc = mt.z;
  if (loc >= Bc) loc = 0;             // unreachable in practice
  const int n_pos = B - 1;
  const int n_neg = K - B;
  const float* simrow = g_sims + mt.w + (size_t)loc * Bc;

  // anchor row chunks for this lane's sub-position (4 lanes cover a row)
  const int s = lane & 3, g = lane >> 2;
  const uint4* fi4 = (const uint4*)(Fh + (size_t)i * 256);
  uint4 fi[8];
#pragma unroll
  for (int k = 0; k < 8; ++k) fi[k] = fi4[k * 4 + s];

  // sim row -> 5 registers (Bc <= 320)
  float v[5];
#pragma unroll
  for (int rr = 0; rr < 5; ++rr) {
    const int t = lane + rr * 64;
    v[rr] = (t < Bc) ? simrow[t] : -3.4e38f;
  }

  int t6 = n_neg < MAXP ? n_neg : MAXP;
  if (t6 < 1) t6 = 1;
  int take = n_pos < t6 ? n_pos : t6;
  if (n_pos <= 0 || n_neg <= 0) take = 0;

  // top-take positives: register argmax + shfl_xor butterfly
  float num = 0.0f;
  for (int r = 0; r < take; ++r) {
    float best = -3.4e38f;
    int bi = 0x7FFFFFFF;
#pragma unroll
    for (int rr = 0; rr < 5; ++rr) {
      if (v[rr] > best) { best = v[rr]; bi = rr * 64 + lane; }
    }
#pragma unroll
    for (int o = 1; o < 64; o <<= 1) {
      const float ov = __shfl_xor(best, o, 64);
      const int oi = __shfl_xor(bi, o, 64);
      if (ov > best || (ov == best && oi < bi)) { best = ov; bi = oi; }
    }
    num += expf(best);
    const int rsel = bi >> 6;
    if ((bi & 63) == lane) {
#pragma unroll
      for (int rr = 0; rr < 5; ++rr)
        if (rr == rsel) v[rr] = -3.4e38f;
    }
  }

  // sample negatives: lane t draws uniform r in [0,n_neg), dedup via shuffles
  const int target = (take > 0) ? (n_neg < NEGK ? n_neg : NEGK) : 0;
  unsigned int rdraw = 0x40000000u + lane;  // distinct out-of-range sentinel
  if (lane < target) {
    const uint64_t z = mix64(((uint64_t)(uint32_t)i << 32) | (uint32_t)lane);
    rdraw = (unsigned int)(((uint64_t)(uint32_t)z * (uint64_t)n_neg) >> 32);
  }
  for (int round = 0; round < 8; ++round) {
    bool dup = false;
    for (int l2 = 0; l2 < NEGK; ++l2) {
      const unsigned int vv = __shfl(rdraw, l2, 64);
      if (l2 < lane && vv == rdraw) dup = true;
    }
    if (!__any(dup)) break;
    if (dup && lane < target) {
      const uint64_t z =
          mix64(((uint64_t)(uint32_t)i << 32) | (uint32_t)(lane + 64 * (round + 1)));
      rdraw = (unsigned int)(((uint64_t)(uint32_t)z * (uint64_t)n_neg) >> 32);
    }
  }
  int myj = 0;
  if (lane < target) {
    const int pos = (rdraw < (unsigned int)bs) ? (int)rdraw : (int)rdraw + B;
    myj = g_bucket[pos];
  }

  // negative dots: 4 lanes per negative, 16 rows in flight per vmem instr;
  // each wave instruction reads 16 fully-consumed 64B lines.
  float e = 0.0f;
#pragma unroll
  for (int r = 0; r < 2; ++r) {
    const int t = r * 16 + g;
    const int j = __shfl(myj, t, 64);
    const uint4* fj = (const uint4*)(Fh + (size_t)j * 256);
    float d = 0.0f;
#pragma unroll
    for (int k = 0; k < 8; ++k) d = dot8h(fj[k * 4 + s], fi[k], d);
    d += __shfl_xor(d, 1, 64);
    d += __shfl_xor(d, 2, 64);
    if (s == 0 && t < target) e += expf(d * 10.0f);
  }
  const float wsum = wave_reduce_add(e);

  if (lane == 0) {
    const float denom = num + wsum;
    float ratio = denom > 0.0f ? num / denom : 0.0f;
    ratio = fmaxf(ratio, 1e-8f);
    g_part[i] = -logf(ratio);           // plain store, no atomics
  }
}

// ---- reduce 8192 per-anchor losses -> mean ----
__global__ __launch_bounds__(1024) void k_final(const float* __restrict__ g_part,
                                                float* __restrict__ out, int K) {
  __shared__ float s[16];
  float p = 0.0f;
  for (int t = threadIdx.x; t < K; t += 1024) p += g_part[t];
  p = wave_reduce_add(p);
  if ((threadIdx.x & 63) == 0) s[threadIdx.x >> 6] = p;
  __syncthreads();
  if (threadIdx.x == 0) {
    float tot = 0.0f;
#pragma unroll
    for (int w = 0; w < 16; ++w) tot += s[w];
    out[0] = tot / (float)K;
  }
}

extern "C" void kernel_launch(void* const* d_in, const int* in_sizes, int n_in,
                              void* d_out, int out_size, void* d_ws, size_t ws_size,
                              hipStream_t stream) {
  (void)n_in; (void)out_size; (void)ws_size;
  const float* F = (const float*)d_in[0];
  const int* labels = (const int*)d_in[1];
  const int K = in_sizes[1];  // 8192; D=256 hard-assumed
  float* out = (float*)d_out;

  char* ws = (char*)d_ws;
  size_t off = 0;
  int*   g_start  = (int*)(ws + off);   off += 512;
  int*   g_soff   = (int*)(ws + off);   off += 256;
  int*   g_bucket = (int*)(ws + off);   off += (size_t)K * 4;
  float* g_part   = (float*)(ws + off); off += (size_t)K * 4;
  off = (off + 255) & ~(size_t)255;
  int4*  g_meta   = (int4*)(ws + off);  off += (size_t)K * 16;
  __half* Fh      = (__half*)(ws + off); off += (size_t)K * 256 * 2;
  float* g_sims   = (float*)(ws + off);  off += (size_t)MAXBC * K * 4;

  k_prep<<<K / 4 + 1, 256, 0, stream>>>(F, labels, K, Fh, g_start, g_soff,
                                        g_bucket, g_meta);
  {
    dim3 grid(64, (MAXBC + RGB - 1) / RGB, (MAXBC + CGB - 1) / CGB);
    k_gram<<<grid, 256, 0, stream>>>(Fh, g_start, g_soff, g_bucket, g_sims);
  }
  k_anchor<<<K / 4, 256, 0, stream>>>(Fh, g_bucket, g_meta, g_sims, g_part, K);
  k_final<<<1, 1024, 0, stream>>>(g_part, out, K);
}